// Round 1
// baseline (218.057 us; speedup 1.0000x reference)
//
#include <hip/hip_runtime.h>
#include <math.h>

#define FEATS 32
#define NNODE 33
#define HID   1024
#define INGRU 68640   // 33*32*65
#define ROWS3 3072    // 3*HID

__device__ __forceinline__ float lrelu(float x) { return x > 0.f ? x : 0.2f * x; }
__device__ __forceinline__ float sigm(float x)  { return 1.f / (1.f + expf(-x)); }

// ---------------------------------------------------------------------------
// K1: build x_in [33,32,65] from the two GATs.
// Key algebra: x[0]=0 -> z[0]=0 -> er[0]=0 (arf/art unused), and
// z[n][h][o] = x[n]*W[h*out+o] factorizes, so the node-0 aggregate is
// agg0[h][o] = s[h]*W[h*out+o] with s[h] = sum_n alpha[n][h]*x[n].
// ---------------------------------------------------------------------------
__global__ void __launch_bounds__(1024) prep_kernel(
    const float* __restrict__ data,
    const float* __restrict__ Wf, const float* __restrict__ alf,
    const float* __restrict__ bf,
    const float* __restrict__ Wt, const float* __restrict__ alt,
    const float* __restrict__ bt,
    float* __restrict__ x_in)
{
    __shared__ float sd[1024];   // d[32][32]
    __shared__ float sSa[32];    // Sa[h] = sum_o Wf[h][o]*alf[h][o]
    __shared__ float sS[32];     // feature-GAT hub scalar per head
    __shared__ float sSt[32];    // time-GAT hub scalar per feature-row
    __shared__ float sCa;        // sum_o Wt[o]*alt[o]

    const int tid = threadIdx.x;
    sd[tid] = data[tid];
    __syncthreads();

    if (tid < 32) {
        float acc = 0.f;
        for (int o = 0; o < 32; ++o) acc += Wf[tid * 32 + o] * alf[tid * 32 + o];
        sSa[tid] = acc;
    } else if (tid == 32) {
        float acc = 0.f;
        for (int o = 0; o < 32; ++o) acc += Wt[o] * alt[o];
        sCa = acc;
    }
    __syncthreads();

    if (tid < 32) {
        // feature GAT, head h = tid; x[n] = d[31][n-1]
        const float Sa = sSa[tid];
        float m = 0.f;                               // n=0 term: e=lrelu(0)=0
        for (int n = 1; n <= 32; ++n)
            m = fmaxf(m, lrelu(sd[31 * 32 + (n - 1)] * Sa));
        float den = expf(0.f - m);                   // n = 0
        float num = 0.f;                             // n = 0 contributes x=0
        for (int n = 1; n <= 32; ++n) {
            float x = sd[31 * 32 + (n - 1)];
            float w = expf(lrelu(x * Sa) - m);
            den += w; num += w * x;
        }
        sS[tid] = num / den;
    } else if (tid >= 64 && tid < 96) {
        // time GAT, feature row i; x[u] = d[i][u-1]
        const int i = tid - 64;
        const float ca = sCa;
        float m = 0.f;
        for (int u = 1; u <= 32; ++u)
            m = fmaxf(m, lrelu(sd[i * 32 + (u - 1)] * ca));
        float den = expf(0.f - m);
        float num = 0.f;
        for (int u = 1; u <= 32; ++u) {
            float y = sd[i * 32 + (u - 1)];
            float w = expf(lrelu(y * ca) - m);
            den += w; num += w * y;
        }
        sSt[i] = num / den;
    }
    __syncthreads();

    // x_in[n][h][0..64] = [ d3 | feat_r(32) | time_r(32) ]
    for (int p = tid; p < NNODE * 32; p += 1024) {
        const int n = p >> 5, h = p & 31;
        float* out = x_in + p * 65;
        out[0] = (n == 0) ? 0.f : sd[(n - 1) * 32 + h];
        const float vf = (n == 0) ? sS[h]  : sd[31 * 32 + (n - 1)];
        const float vt = (n == 0) ? sSt[h] : sd[h * 32 + (n - 1)];
        for (int o = 0; o < 32; ++o) {
            out[1 + o]  = vf * Wf[h * 32 + o] + bf[h * 32 + o];
            out[33 + o] = vt * Wt[o] + bt[o];
        }
    }
}

// ---------------------------------------------------------------------------
// K2/K4: two matvecs in one grid. Blocks [0,3072): y0 = A0 @ x0 + b0,
// blocks [3072,6144): y1 = A1 @ x1 + b1. One row per block, float4 loads,
// wave-64 shuffle reduce + cross-wave LDS reduce.
// ---------------------------------------------------------------------------
__global__ void __launch_bounds__(256) matvec_pair(
    const float* __restrict__ A0, const float* __restrict__ x0,
    const float* __restrict__ b0, float* __restrict__ y0, int n4_0,
    const float* __restrict__ A1, const float* __restrict__ x1,
    const float* __restrict__ b1, float* __restrict__ y1, int n4_1)
{
    const int row = blockIdx.x;
    const float4* A; const float4* X; float bias; float* out; int n4;
    if (row < ROWS3) {
        A = (const float4*)A0 + (size_t)row * n4_0;
        X = (const float4*)x0; bias = b0[row]; out = y0 + row; n4 = n4_0;
    } else {
        const int r = row - ROWS3;
        A = (const float4*)A1 + (size_t)r * n4_1;
        X = (const float4*)x1; bias = b1[r]; out = y1 + r; n4 = n4_1;
    }
    float acc = 0.f;
    for (int k = threadIdx.x; k < n4; k += 256) {
        const float4 a = A[k];
        const float4 x = X[k];
        acc += a.x * x.x + a.y * x.y + a.z * x.z + a.w * x.w;
    }
    for (int off = 32; off; off >>= 1) acc += __shfl_down(acc, off);
    __shared__ float red[4];
    const int lane = threadIdx.x & 63, wv = threadIdx.x >> 6;
    if (lane == 0) red[wv] = acc;
    __syncthreads();
    if (threadIdx.x == 0) *out = red[0] + red[1] + red[2] + red[3] + bias;
}

// ---------------------------------------------------------------------------
// K3/K5: GRU pointwise cell. 1024 threads total.
// ---------------------------------------------------------------------------
__global__ void __launch_bounds__(256) gru_cell(
    const float* __restrict__ gi, const float* __restrict__ gh,
    const float* __restrict__ hprev,
    float* __restrict__ hout, float* __restrict__ hout2, float* __restrict__ hout3)
{
    const int j = blockIdx.x * blockDim.x + threadIdx.x;
    const float r  = sigm(gi[j] + gh[j]);
    const float zg = sigm(gi[HID + j] + gh[HID + j]);
    const float n  = tanhf(gi[2 * HID + j] + r * gh[2 * HID + j]);
    const float h  = (1.f - zg) * n + zg * hprev[j];
    hout[j] = h;
    if (hout2) hout2[j] = h;
    if (hout3) hout3[j] = h;
}

extern "C" void kernel_launch(void* const* d_in, const int* in_sizes, int n_in,
                              void* d_out, int out_size, void* d_ws, size_t ws_size,
                              hipStream_t stream)
{
    const float* data   = (const float*)d_in[0];
    const float* hidden = (const float*)d_in[1];
    const float* Wf     = (const float*)d_in[2];
    const float* alf    = (const float*)d_in[3];
    // d_in[4] = arf: provably unused (er[0] == 0 since hub input is 0)
    const float* bf     = (const float*)d_in[5];
    const float* Wt     = (const float*)d_in[6];
    const float* alt    = (const float*)d_in[7];
    // d_in[8] = art: unused
    const float* bt     = (const float*)d_in[9];
    const float* w_ih0  = (const float*)d_in[10];
    const float* w_hh0  = (const float*)d_in[11];
    const float* b_ih0  = (const float*)d_in[12];
    const float* b_hh0  = (const float*)d_in[13];
    const float* w_ih1  = (const float*)d_in[14];
    const float* w_hh1  = (const float*)d_in[15];
    const float* b_ih1  = (const float*)d_in[16];
    const float* b_hh1  = (const float*)d_in[17];

    float* out  = (float*)d_out;       // [h1 (1024) | h0 (1024) | h1 (1024)]
    float* ws   = (float*)d_ws;
    float* x_in = ws;                  // 68640
    float* gi0  = ws + INGRU;          // 3072
    float* gh0  = gi0 + ROWS3;         // 3072
    float* h0   = gh0 + ROWS3;         // 1024
    float* gi1  = h0 + HID;            // 3072
    float* gh1  = gi1 + ROWS3;         // 3072

    prep_kernel<<<1, 1024, 0, stream>>>(data, Wf, alf, bf, Wt, alt, bt, x_in);

    matvec_pair<<<2 * ROWS3, 256, 0, stream>>>(
        w_ih0, x_in,   b_ih0, gi0, INGRU / 4,
        w_hh0, hidden, b_hh0, gh0, HID / 4);

    gru_cell<<<4, 256, 0, stream>>>(gi0, gh0, hidden, h0, out + HID, nullptr);

    matvec_pair<<<2 * ROWS3, 256, 0, stream>>>(
        w_ih1, h0,           b_ih1, gi1, HID / 4,
        w_hh1, hidden + HID, b_hh1, gh1, HID / 4);

    gru_cell<<<4, 256, 0, stream>>>(gi1, gh1, hidden + HID, out, out + 2 * HID, nullptr);
}

// Round 2
// 176.904 us; speedup vs baseline: 1.2326x; 1.2326x over previous
//
#include <hip/hip_runtime.h>
#include <math.h>

#define FEATS 32
#define NNODE 33
#define HID   1024
#define INGRU 68640        // 33*32*65
#define ROWS3 3072         // 3*HID
#define N4BIG 17160        // INGRU/4 float4s per w_ih0 row
#define CHUNKS 8
#define CHLEN  2145        // N4BIG / CHUNKS (exact)

__device__ __forceinline__ float lrelu(float x) { return x > 0.f ? x : 0.2f * x; }
__device__ __forceinline__ float sigm(float x)  { return 1.f / (1.f + expf(-x)); }

// ---------------------------------------------------------------------------
// K1: build x_in [33 nodes][32 heads][65] — one block per node, coalesced
// contiguous writes of the node's 2080-float slice. Block 33 zeroes gi0
// (atomic accumulator target; re-zeroed every call for graph-replay
// determinism). GAT algebra: hub input is 0 -> er[0]=0 (arf/art unused);
// z factorizes so the hub aggregate is a scalar per head.
// ---------------------------------------------------------------------------
__global__ void __launch_bounds__(256) prep_kernel(
    const float* __restrict__ data,
    const float* __restrict__ Wf, const float* __restrict__ alf,
    const float* __restrict__ bf,
    const float* __restrict__ Wt, const float* __restrict__ alt,
    const float* __restrict__ bt,
    float* __restrict__ x_in, float* __restrict__ gi0_zero)
{
    const int n = blockIdx.x;
    const int tid = threadIdx.x;

    if (n == NNODE) {                       // zero the atomic target
        for (int i = tid; i < ROWS3; i += 256) gi0_zero[i] = 0.f;
        return;
    }

    __shared__ float sS[32];                // feature-GAT hub scalar per head
    __shared__ float sSt[32];               // time-GAT hub scalar per feature

    if (n == 0) {
        if (tid < 32) {
            float Sa = 0.f;
            for (int o = 0; o < 32; ++o) Sa += Wf[tid * 32 + o] * alf[tid * 32 + o];
            float m = 0.f;                  // hub self-edge: e = lrelu(0) = 0
            for (int u = 1; u <= 32; ++u)
                m = fmaxf(m, lrelu(data[31 * 32 + u - 1] * Sa));
            float den = expf(-m), num = 0.f;
            for (int u = 1; u <= 32; ++u) {
                float x = data[31 * 32 + u - 1];
                float w = expf(lrelu(x * Sa) - m);
                den += w; num += w * x;
            }
            sS[tid] = num / den;
        } else if (tid < 64) {
            const int i = tid - 32;
            float ca = 0.f;
            for (int o = 0; o < 32; ++o) ca += Wt[o] * alt[o];
            float m = 0.f;
            for (int u = 1; u <= 32; ++u)
                m = fmaxf(m, lrelu(data[i * 32 + u - 1] * ca));
            float den = expf(-m), num = 0.f;
            for (int u = 1; u <= 32; ++u) {
                float y = data[i * 32 + u - 1];
                float w = expf(lrelu(y * ca) - m);
                den += w; num += w * y;
            }
            sSt[i] = num / den;
        }
        __syncthreads();
    }

    float* out = x_in + n * 2080;           // node slice is contiguous
    for (int q = tid; q < 2080; q += 256) {
        const int h = q / 65, c = q % 65;
        float v;
        if (c == 0) {
            v = (n == 0) ? 0.f : data[(n - 1) * 32 + h];
        } else if (c < 33) {
            const float vf = (n == 0) ? sS[h] : data[31 * 32 + (n - 1)];
            v = vf * Wf[h * 32 + (c - 1)] + bf[h * 32 + (c - 1)];
        } else {
            const float vt = (n == 0) ? sSt[h] : data[h * 32 + (n - 1)];
            v = vt * Wt[c - 33] + bt[c - 33];
        }
        out[q] = v;
    }
}

// ---------------------------------------------------------------------------
// K2: layer-0 matvecs. Blocks [0, 3072*8): gi0 += chunk-dot of w_ih0 —
// bid = row*8 + chunk so consecutive blocks stream consecutive memory
// (dense sliding window over the 843 MB matrix). One f32 atomicAdd per
// chunk. Blocks [24576, 27648): gh0 rows (1024-col), plain store.
// No biases here — folded into gru_cell.
// ---------------------------------------------------------------------------
__global__ void __launch_bounds__(256) mv_big(
    const float* __restrict__ A0, const float* __restrict__ x0,
    float* __restrict__ y0,
    const float* __restrict__ A1, const float* __restrict__ x1,
    float* __restrict__ y1)
{
    const int tid = threadIdx.x;
    float acc = 0.f;
    float* dst;
    bool is_big;

    if (blockIdx.x < ROWS3 * CHUNKS) {
        is_big = true;
        const int row = blockIdx.x >> 3, c = blockIdx.x & 7;
        const float4* A = (const float4*)A0 + (size_t)row * N4BIG + c * CHLEN;
        const float4* X = (const float4*)x0 + c * CHLEN;
        for (int k = tid; k < CHLEN; k += 256) {
            const float4 a = A[k];
            const float4 x = X[k];
            acc += a.x * x.x + a.y * x.y + a.z * x.z + a.w * x.w;
        }
        dst = y0 + row;
    } else {
        is_big = false;
        const int r = blockIdx.x - ROWS3 * CHUNKS;
        const float4* A = (const float4*)A1 + (size_t)r * 256;
        const float4* X = (const float4*)x1;
        const float4 a = A[tid];
        const float4 x = X[tid];
        acc = a.x * x.x + a.y * x.y + a.z * x.z + a.w * x.w;
        dst = y1 + r;
    }

    for (int off = 32; off; off >>= 1) acc += __shfl_down(acc, off);
    __shared__ float red[4];
    if ((tid & 63) == 0) red[tid >> 6] = acc;
    __syncthreads();
    if (tid == 0) {
        const float tot = red[0] + red[1] + red[2] + red[3];
        if (is_big) atomicAdd(dst, tot);
        else        *dst = tot;
    }
}

// ---------------------------------------------------------------------------
// K4: layer-1 matvecs (both 3072x1024, plain store, no bias).
// ---------------------------------------------------------------------------
__global__ void __launch_bounds__(256) mv_small(
    const float* __restrict__ A0, const float* __restrict__ x0,
    float* __restrict__ y0,
    const float* __restrict__ A1, const float* __restrict__ x1,
    float* __restrict__ y1)
{
    const int tid = threadIdx.x;
    const float4* A; const float4* X; float* dst;
    if (blockIdx.x < ROWS3) {
        A = (const float4*)A0 + (size_t)blockIdx.x * 256;
        X = (const float4*)x0;
        dst = y0 + blockIdx.x;
    } else {
        const int r = blockIdx.x - ROWS3;
        A = (const float4*)A1 + (size_t)r * 256;
        X = (const float4*)x1;
        dst = y1 + r;
    }
    const float4 a = A[tid];
    const float4 x = X[tid];
    float acc = a.x * x.x + a.y * x.y + a.z * x.z + a.w * x.w;

    for (int off = 32; off; off >>= 1) acc += __shfl_down(acc, off);
    __shared__ float red[4];
    if ((tid & 63) == 0) red[tid >> 6] = acc;
    __syncthreads();
    if (tid == 0) *dst = red[0] + red[1] + red[2] + red[3];
}

// ---------------------------------------------------------------------------
// K3/K5: GRU pointwise cell with biases folded in (gi/gh are raw dots).
// n-gate: tanh(i_n + r * h_n) with h_n = gh + b_hh (bias inside the r*()).
// ---------------------------------------------------------------------------
__global__ void __launch_bounds__(256) gru_cell(
    const float* __restrict__ gi, const float* __restrict__ gh,
    const float* __restrict__ bih, const float* __restrict__ bhh,
    const float* __restrict__ hprev,
    float* __restrict__ hout, float* __restrict__ hout2, float* __restrict__ hout3)
{
    const int j = blockIdx.x * blockDim.x + threadIdx.x;
    const float r  = sigm(gi[j] + bih[j] + gh[j] + bhh[j]);
    const float zg = sigm(gi[HID + j] + bih[HID + j] + gh[HID + j] + bhh[HID + j]);
    const float n  = tanhf(gi[2 * HID + j] + bih[2 * HID + j]
                           + r * (gh[2 * HID + j] + bhh[2 * HID + j]));
    const float h  = (1.f - zg) * n + zg * hprev[j];
    hout[j] = h;
    if (hout2) hout2[j] = h;
    if (hout3) hout3[j] = h;
}

extern "C" void kernel_launch(void* const* d_in, const int* in_sizes, int n_in,
                              void* d_out, int out_size, void* d_ws, size_t ws_size,
                              hipStream_t stream)
{
    const float* data   = (const float*)d_in[0];
    const float* hidden = (const float*)d_in[1];
    const float* Wf     = (const float*)d_in[2];
    const float* alf    = (const float*)d_in[3];
    // d_in[4] = arf: provably unused (hub input is 0 -> er[0] == 0)
    const float* bf     = (const float*)d_in[5];
    const float* Wt     = (const float*)d_in[6];
    const float* alt    = (const float*)d_in[7];
    // d_in[8] = art: unused
    const float* bt     = (const float*)d_in[9];
    const float* w_ih0  = (const float*)d_in[10];
    const float* w_hh0  = (const float*)d_in[11];
    const float* b_ih0  = (const float*)d_in[12];
    const float* b_hh0  = (const float*)d_in[13];
    const float* w_ih1  = (const float*)d_in[14];
    const float* w_hh1  = (const float*)d_in[15];
    const float* b_ih1  = (const float*)d_in[16];
    const float* b_hh1  = (const float*)d_in[17];

    float* out  = (float*)d_out;       // [h1 (1024) | h0 (1024) | h1 (1024)]
    float* ws   = (float*)d_ws;
    float* x_in = ws;                  // 68640
    float* gi0  = ws + INGRU;          // 3072 (atomic accumulator, zeroed in prep)
    float* gh0  = gi0 + ROWS3;         // 3072
    float* h0   = gh0 + ROWS3;         // 1024
    float* gi1  = h0 + HID;            // 3072
    float* gh1  = gi1 + ROWS3;         // 3072

    prep_kernel<<<NNODE + 1, 256, 0, stream>>>(data, Wf, alf, bf, Wt, alt, bt,
                                               x_in, gi0);

    mv_big<<<ROWS3 * CHUNKS + ROWS3, 256, 0, stream>>>(
        w_ih0, x_in, gi0,
        w_hh0, hidden, gh0);

    gru_cell<<<4, 256, 0, stream>>>(gi0, gh0, b_ih0, b_hh0, hidden,
                                    h0, out + HID, nullptr);

    mv_small<<<2 * ROWS3, 256, 0, stream>>>(
        w_ih1, h0, gi1,
        w_hh1, hidden + HID, gh1);

    gru_cell<<<4, 256, 0, stream>>>(gi1, gh1, b_ih1, b_hh1, hidden + HID,
                                    out, out + 2 * HID, nullptr);
}

// Round 4
// 171.238 us; speedup vs baseline: 1.2734x; 1.0331x over previous
//
#include <hip/hip_runtime.h>
#include <math.h>

#define FEATS 32
#define NNODE 33
#define HID   1024
#define INGRU 68640        // 33*32*65
#define ROWS3 3072         // 3*HID
#define N4BIG 17160        // INGRU/4 float4s per w_ih0 row
#define CHUNKS 8
#define CHLEN  2145        // N4BIG / CHUNKS (exact)
#define CHMAIN 2048        // 8 * 256
#define CHTAIL 97          // CHLEN - CHMAIN

typedef float f4 __attribute__((ext_vector_type(4)));   // clang-native vec for nt loads

__device__ __forceinline__ float lrelu(float x) { return x > 0.f ? x : 0.2f * x; }
__device__ __forceinline__ float sigm(float x)  { return 1.f / (1.f + expf(-x)); }
__device__ __forceinline__ float dot4(f4 a, f4 b) {
    return a.x * b.x + a.y * b.y + a.z * b.z + a.w * b.w;
}

// ---------------------------------------------------------------------------
// K1: build x_in [33 nodes][32 heads][65] — one block per node, coalesced
// contiguous writes. Block 33 zeroes gi0 (atomic target; re-zeroed every
// call for graph-replay determinism). GAT algebra: hub input is 0 ->
// er[0]=0 (arf/art unused); z factorizes so hub aggregate is scalar/head.
// ---------------------------------------------------------------------------
__global__ void __launch_bounds__(256) prep_kernel(
    const float* __restrict__ data,
    const float* __restrict__ Wf, const float* __restrict__ alf,
    const float* __restrict__ bf,
    const float* __restrict__ Wt, const float* __restrict__ alt,
    const float* __restrict__ bt,
    float* __restrict__ x_in, float* __restrict__ gi0_zero)
{
    const int n = blockIdx.x;
    const int tid = threadIdx.x;

    if (n == NNODE) {
        for (int i = tid; i < ROWS3; i += 256) gi0_zero[i] = 0.f;
        return;
    }

    __shared__ float sS[32];                // feature-GAT hub scalar per head
    __shared__ float sSt[32];               // time-GAT hub scalar per feature

    if (n == 0) {
        if (tid < 32) {
            float Sa = 0.f;
            for (int o = 0; o < 32; ++o) Sa += Wf[tid * 32 + o] * alf[tid * 32 + o];
            float m = 0.f;                  // hub self-edge: e = lrelu(0) = 0
            for (int u = 1; u <= 32; ++u)
                m = fmaxf(m, lrelu(data[31 * 32 + u - 1] * Sa));
            float den = expf(-m), num = 0.f;
            for (int u = 1; u <= 32; ++u) {
                float x = data[31 * 32 + u - 1];
                float w = expf(lrelu(x * Sa) - m);
                den += w; num += w * x;
            }
            sS[tid] = num / den;
        } else if (tid < 64) {
            const int i = tid - 32;
            float ca = 0.f;
            for (int o = 0; o < 32; ++o) ca += Wt[o] * alt[o];
            float m = 0.f;
            for (int u = 1; u <= 32; ++u)
                m = fmaxf(m, lrelu(data[i * 32 + u - 1] * ca));
            float den = expf(-m), num = 0.f;
            for (int u = 1; u <= 32; ++u) {
                float y = data[i * 32 + u - 1];
                float w = expf(lrelu(y * ca) - m);
                den += w; num += w * y;
            }
            sSt[i] = num / den;
        }
        __syncthreads();
    }

    float* out = x_in + n * 2080;           // node slice is contiguous
    for (int q = tid; q < 2080; q += 256) {
        const int h = q / 65, c = q % 65;
        float v;
        if (c == 0) {
            v = (n == 0) ? 0.f : data[(n - 1) * 32 + h];
        } else if (c < 33) {
            const float vf = (n == 0) ? sS[h] : data[31 * 32 + (n - 1)];
            v = vf * Wf[h * 32 + (c - 1)] + bf[h * 32 + (c - 1)];
        } else {
            const float vt = (n == 0) ? sSt[h] : data[h * 32 + (n - 1)];
            v = vt * Wt[c - 33] + bt[c - 33];
        }
        out[q] = v;
    }
}

// ---------------------------------------------------------------------------
// K2: layer-0 matvecs. bid = row*8 + chunk => consecutive blocks stream
// consecutive memory (dense sliding window over the 843 MB matrix).
// A-loads are NONTEMPORAL (read-once stream; keep X resident in L2).
// Inner loop hand-unrolled: 8 x 256 float4 pairs issued up front + 97 tail.
// One f32 atomicAdd per chunk. Biases folded into gru_cell.
// ---------------------------------------------------------------------------
__global__ void __launch_bounds__(256) mv_big(
    const float* __restrict__ A0, const float* __restrict__ x0,
    float* __restrict__ y0,
    const float* __restrict__ A1, const float* __restrict__ x1,
    float* __restrict__ y1)
{
    const int tid = threadIdx.x;
    float acc = 0.f;
    float* dst;
    bool is_big;

    if (blockIdx.x < ROWS3 * CHUNKS) {
        is_big = true;
        const int row = blockIdx.x >> 3, c = blockIdx.x & 7;
        const f4* A = (const f4*)A0 + (size_t)row * N4BIG + c * CHLEN;
        const f4* X = (const f4*)x0 + c * CHLEN;

        f4 a[8], x[8];
#pragma unroll
        for (int i = 0; i < 8; ++i)
            a[i] = __builtin_nontemporal_load(&A[tid + i * 256]);
#pragma unroll
        for (int i = 0; i < 8; ++i)
            x[i] = X[tid + i * 256];
        float acc2 = 0.f;
#pragma unroll
        for (int i = 0; i < 8; i += 2) {
            acc  += dot4(a[i],     x[i]);
            acc2 += dot4(a[i + 1], x[i + 1]);
        }
        if (tid < CHTAIL) {
            const f4 at = __builtin_nontemporal_load(&A[CHMAIN + tid]);
            const f4 xt = X[CHMAIN + tid];
            acc2 += dot4(at, xt);
        }
        acc += acc2;
        dst = y0 + row;
    } else {
        is_big = false;
        const int r = blockIdx.x - ROWS3 * CHUNKS;
        const f4* A = (const f4*)A1 + (size_t)r * 256;
        const f4 a = __builtin_nontemporal_load(&A[tid]);
        const f4 x = ((const f4*)x1)[tid];
        acc = dot4(a, x);
        dst = y1 + r;
    }

    for (int off = 32; off; off >>= 1) acc += __shfl_down(acc, off);
    __shared__ float red[4];
    if ((tid & 63) == 0) red[tid >> 6] = acc;
    __syncthreads();
    if (tid == 0) {
        const float tot = red[0] + red[1] + red[2] + red[3];
        if (is_big) atomicAdd(dst, tot);
        else        *dst = tot;
    }
}

// ---------------------------------------------------------------------------
// K4: layer-1 matvecs (both 3072x1024, plain store, no bias).
// ---------------------------------------------------------------------------
__global__ void __launch_bounds__(256) mv_small(
    const float* __restrict__ A0, const float* __restrict__ x0,
    float* __restrict__ y0,
    const float* __restrict__ A1, const float* __restrict__ x1,
    float* __restrict__ y1)
{
    const int tid = threadIdx.x;
    const f4* A; const f4* X; float* dst;
    if (blockIdx.x < ROWS3) {
        A = (const f4*)A0 + (size_t)blockIdx.x * 256;
        X = (const f4*)x0;
        dst = y0 + blockIdx.x;
    } else {
        const int r = blockIdx.x - ROWS3;
        A = (const f4*)A1 + (size_t)r * 256;
        X = (const f4*)x1;
        dst = y1 + r;
    }
    const f4 a = __builtin_nontemporal_load(&A[tid]);
    const f4 x = X[tid];
    float acc = dot4(a, x);

    for (int off = 32; off; off >>= 1) acc += __shfl_down(acc, off);
    __shared__ float red[4];
    if ((tid & 63) == 0) red[tid >> 6] = acc;
    __syncthreads();
    if (tid == 0) *dst = red[0] + red[1] + red[2] + red[3];
}

// ---------------------------------------------------------------------------
// K3/K5: GRU pointwise cell with biases folded in (gi/gh are raw dots).
// ---------------------------------------------------------------------------
__global__ void __launch_bounds__(256) gru_cell(
    const float* __restrict__ gi, const float* __restrict__ gh,
    const float* __restrict__ bih, const float* __restrict__ bhh,
    const float* __restrict__ hprev,
    float* __restrict__ hout, float* __restrict__ hout2, float* __restrict__ hout3)
{
    const int j = blockIdx.x * blockDim.x + threadIdx.x;
    const float r  = sigm(gi[j] + bih[j] + gh[j] + bhh[j]);
    const float zg = sigm(gi[HID + j] + bih[HID + j] + gh[HID + j] + bhh[HID + j]);
    const float n  = tanhf(gi[2 * HID + j] + bih[2 * HID + j]
                           + r * (gh[2 * HID + j] + bhh[2 * HID + j]));
    const float h  = (1.f - zg) * n + zg * hprev[j];
    hout[j] = h;
    if (hout2) hout2[j] = h;
    if (hout3) hout3[j] = h;
}

extern "C" void kernel_launch(void* const* d_in, const int* in_sizes, int n_in,
                              void* d_out, int out_size, void* d_ws, size_t ws_size,
                              hipStream_t stream)
{
    const float* data   = (const float*)d_in[0];
    const float* hidden = (const float*)d_in[1];
    const float* Wf     = (const float*)d_in[2];
    const float* alf    = (const float*)d_in[3];
    // d_in[4] = arf: provably unused (hub input is 0 -> er[0] == 0)
    const float* bf     = (const float*)d_in[5];
    const float* Wt     = (const float*)d_in[6];
    const float* alt    = (const float*)d_in[7];
    // d_in[8] = art: unused
    const float* bt     = (const float*)d_in[9];
    const float* w_ih0  = (const float*)d_in[10];
    const float* w_hh0  = (const float*)d_in[11];
    const float* b_ih0  = (const float*)d_in[12];
    const float* b_hh0  = (const float*)d_in[13];
    const float* w_ih1  = (const float*)d_in[14];
    const float* w_hh1  = (const float*)d_in[15];
    const float* b_ih1  = (const float*)d_in[16];
    const float* b_hh1  = (const float*)d_in[17];

    float* out  = (float*)d_out;       // [h1 (1024) | h0 (1024) | h1 (1024)]
    float* ws   = (float*)d_ws;
    float* x_in = ws;                  // 68640
    float* gi0  = ws + INGRU;          // 3072 (atomic accumulator, zeroed in prep)
    float* gh0  = gi0 + ROWS3;         // 3072
    float* h0   = gh0 + ROWS3;         // 1024
    float* gi1  = h0 + HID;            // 3072
    float* gh1  = gi1 + ROWS3;         // 3072

    prep_kernel<<<NNODE + 1, 256, 0, stream>>>(data, Wf, alf, bf, Wt, alt, bt,
                                               x_in, gi0);

    mv_big<<<ROWS3 * CHUNKS + ROWS3, 256, 0, stream>>>(
        w_ih0, x_in, gi0,
        w_hh0, hidden, gh0);

    gru_cell<<<4, 256, 0, stream>>>(gi0, gh0, b_ih0, b_hh0, hidden,
                                    h0, out + HID, nullptr);

    mv_small<<<2 * ROWS3, 256, 0, stream>>>(
        w_ih1, h0, gi1,
        w_hh1, hidden + HID, gh1);

    gru_cell<<<4, 256, 0, stream>>>(gi1, gh1, b_ih1, b_hh1, hidden + HID,
                                    out, out + 2 * HID, nullptr);
}